// Round 14
// baseline (17.981 us; speedup 1.0000x reference)
//
#include <hip/hip_runtime.h>
#include <math.h>

#define N 1024
#define D 128
#define CAP 96
#define MAXNORM 0.996f
#define MINN 1e-15f

__device__ __forceinline__ float wave_sum(float v) {
#pragma unroll
    for (int o = 32; o > 0; o >>= 1) v += __shfl_xor(v, o, 64);
    return v;
}

__device__ __forceinline__ void wave_sum2(float& a, float& b) {
#pragma unroll
    for (int o = 32; o > 0; o >>= 1) {
        a += __shfl_xor(a, o, 64);
        b += __shfl_xor(b, o, 64);
    }
}

__device__ __forceinline__ void wave_sum3(float& a, float& b, float& c) {
#pragma unroll
    for (int o = 32; o > 0; o >>= 1) {
        a += __shfl_xor(a, o, 64);
        b += __shfl_xor(b, o, 64);
        c += __shfl_xor(c, o, 64);
    }
}

__device__ __forceinline__ void group16_sum2(float& a, float& b) {
#pragma unroll
    for (int o = 8; o > 0; o >>= 1) {
        a += __shfl_xor(a, o, 64);
        b += __shfl_xor(b, o, 64);
    }
}

__device__ __forceinline__ float group8_sum(float v) {
#pragma unroll
    for (int o = 4; o > 0; o >>= 1) v += __shfl_xor(v, o, 64);
    return v;
}

__device__ __forceinline__ float artanh_fast(float x) {
    x = fminf(fmaxf(x, -1.0f + 1e-7f), 1.0f - 1e-7f);
    return 0.5f * __logf(__fdividef(1.0f + x, 1.0f - x));
}

// tanh for x >= 0 via one v_exp: (1 - e^-2x) / (1 + e^-2x)
__device__ __forceinline__ float tanh_pos(float x) {
    float t = __expf(-2.f * x);
    return __fdividef(1.f - t, 1.f + t);
}

__device__ __forceinline__ float dot44(float4 a, float4 b) {
    return a.x * b.x + a.y * b.y + a.z * b.z + a.w * b.w;
}

// ---- kernel A: one block (4 waves) per TWO rows (i0 = 2*bid, i0+1).
// One set of W loads feeds both rows' matvecs (halves aggregate W L2 traffic).
// Scalar chains run concurrently on waves 0 (row i0) and 1 (row i0+1).
__global__ __launch_bounds__(256) void k_rows(
    const float* __restrict__ x, const float* __restrict__ Wm,
    const float* __restrict__ bias, const float* __restrict__ attw,
    const float* __restrict__ attb_p, const float* __restrict__ adj,
    float* __restrict__ h, float4* __restrict__ rowmeta,
    int2* __restrict__ edge_g) {
    __shared__ float smv[2][D];
    __shared__ int wcnt[2][4];
    const int t = threadIdx.x, w = t >> 6, l = t & 63;
    const int g = l >> 4, m = l & 15;
    const int i0 = blockIdx.x * 2;
    const unsigned long long lt_mask = (1ull << l) - 1ull;

    // issue both adj-row segment loads early (hide HBM under the matvec)
    float4 av0 = *(const float4*)(adj + (size_t)i0 * N + (w << 8) + 4 * l);
    float4 av1 = *(const float4*)(adj + (size_t)(i0 + 1) * N + (w << 8) + 4 * l);

    // x chunks for both rows (reused across all 8 matvec passes)
    float4 xa0 = *(const float4*)(x + (size_t)i0 * D + 4 * m);
    float4 xb0 = *(const float4*)(x + (size_t)i0 * D + 64 + 4 * m);
    float4 xa1 = *(const float4*)(x + (size_t)(i0 + 1) * D + 4 * m);
    float4 xb1 = *(const float4*)(x + (size_t)(i0 + 1) * D + 64 + 4 * m);

    float xn2_0 = dot44(xa0, xa0) + dot44(xb0, xb0);
    float xn2_1 = dot44(xa1, xa1) + dot44(xb1, xb1);
    group16_sum2(xn2_0, xn2_1);

    // matvec: wave w covers outputs [32w,32w+32); group g does output 32w+4p+g
#pragma unroll
    for (int p = 0; p < 8; ++p) {
        const int o = (w << 5) + (p << 2) + g;
        float4 wa = *(const float4*)(Wm + (size_t)o * D + 4 * m);
        float4 wb = *(const float4*)(Wm + (size_t)o * D + 64 + 4 * m);
        float s0 = dot44(wa, xa0) + dot44(wb, xb0);
        float s1 = dot44(wa, xa1) + dot44(wb, xb1);
        group16_sum2(s0, s1);
        if (m == 0) {
            smv[0][o] = s0;
            smv[1][o] = s1;
        }
    }

    // ballot compaction bookkeeping for both rows
    float ae0[4] = {av0.x, av0.y, av0.z, av0.w};
    float ae1[4] = {av1.x, av1.y, av1.z, av1.w};
    unsigned long long msk0[4], msk1[4];
    int cnt0 = 0, cnt1 = 0;
#pragma unroll
    for (int e = 0; e < 4; ++e) {
        msk0[e] = __ballot(ae0[e] != 0.0f);
        cnt0 += __popcll(msk0[e]);
        msk1[e] = __ballot(ae1[e] != 0.0f);
        cnt1 += __popcll(msk1[e]);
    }
    if (l == 0) {
        wcnt[0][w] = cnt0;
        wcnt[1][w] = cnt1;
    }
    __syncthreads();  // [A] publishes smv and wcnt

    int base0 = 0, base1 = 0;
#pragma unroll
    for (int ww = 0; ww < 4; ++ww)
        if (ww < w) {
            base0 += wcnt[0][ww];
            base1 += wcnt[1][ww];
        }
    const int tot0 = wcnt[0][0] + wcnt[0][1] + wcnt[0][2] + wcnt[0][3];
    const int tot1 = wcnt[1][0] + wcnt[1][1] + wcnt[1][2] + wcnt[1][3];
    {
        int off = base0;
#pragma unroll
        for (int e = 0; e < 4; ++e) {
            if (ae0[e] != 0.0f) {
                int pos = off + __popcll(msk0[e] & lt_mask);
                if (pos < CAP)
                    edge_g[i0 * CAP + pos] =
                        make_int2((w << 8) + 4 * l + e, __float_as_int(ae0[e]));
            }
            off += __popcll(msk0[e]);
        }
        off = base1;
#pragma unroll
        for (int e = 0; e < 4; ++e) {
            if (ae1[e] != 0.0f) {
                int pos = off + __popcll(msk1[e] & lt_mask);
                if (pos < CAP)
                    edge_g[(i0 + 1) * CAP + pos] =
                        make_int2((w << 8) + 4 * l + e, __float_as_int(ae1[e]));
            }
            off += __popcll(msk1[e]);
        }
    }

    if (w >= 2) return;

    // ---- wave w in {0,1}: scalar chain for row i0+w; TWO reduction stages.
    const int i = i0 + w;
    const float xn2 = (w == 0) ? xn2_0 : xn2_1;
    const int tot = (w == 0) ? tot0 : tot1;
    const float attb = attb_p[0];
    float2 bv = *(const float2*)(bias + 2 * l);
    float2 mv = *(const float2*)(&smv[w][2 * l]);

    // stage 1: (|mv|^2, |bias|^2, <mv,bias>) batched
    float mxn2 = mv.x * mv.x + mv.y * mv.y;
    float bn2 = bv.x * bv.x + bv.y * bv.y;
    float mvb = mv.x * bv.x + mv.y * bv.y;
    wave_sum3(mxn2, bn2, mvb);

    // bias chain (all scalar): hbv = hbs * bv
    float bn = fmaxf(sqrtf(bn2), MINN);
    float tb = tanh_pos(bn);
    float bsc = tb / bn;
    float clampB = (tb > MAXNORM) ? (MAXNORM / tb) : 1.f;
    float hbs = bsc * clampB;
    float vn = fminf(tb, MAXNORM);
    float y2 = vn * vn;

    // mobius_matvec norm chain (scalar): r = rs * mv
    float mxn = fmaxf(sqrtf(mxn2), MINN);
    float xn = fmaxf(sqrtf(xn2), MINN);
    float rn = tanh_pos(mxn / xn * artanh_fast(xn));  // = |mobius_matvec| >= 0
    float rsc = rn / mxn;
    float sr = (rn > MAXNORM) ? (MAXNORM / rn) : 1.f;
    float rs = rsc * sr;
    float rn_c = rn * sr;
    float x2 = rn_c * rn_c;

    // mobius_add(r, hbv): <r,hbv> = rs*hbs*<mv,bv> (scalar — no reduction)
    float xy = rs * hbs * mvb;
    float den = fmaxf(1.f + 2.f * xy + x2 * y2, MINN);
    float ca = (1.f + 2.f * xy + y2) / den;
    float cb = (1.f - x2) / den;
    float hp0 = ca * rs * mv.x + cb * hbs * bv.x;
    float hp1 = ca * rs * mv.y + cb * hbs * bv.y;

    // stage 2: (|hp|^2, hp.wl, hp.wr) batched on UNSCALED hp (proj is linear)
    float t0 = hp0 * hp0 + hp1 * hp1;
    float t1 = hp0 * attw[2 * l] + hp1 * attw[2 * l + 1];
    float t2 = hp0 * attw[D + 2 * l] + hp1 * attw[D + 2 * l + 1];
    wave_sum3(t0, t1, t2);

    float hn = fmaxf(sqrtf(t0), MINN);
    float sh = (hn > MAXNORM) ? (MAXNORM / hn) : 1.f;
    hp0 *= sh;
    hp1 *= sh;
    float h2 = t0 * sh * sh;
    float hnn = fmaxf(sqrtf(h2), MINN);
    float fac = artanh_fast(hnn) / hnn;
    float sLv = fac * (t1 * sh);
    float sRv = fac * (t2 * sh);

    *(float2*)(h + (size_t)i * D + 2 * l) = make_float2(hp0, hp1);
    if (l == 0) {
        int cl = (tot < CAP) ? tot : CAP;
        rowmeta[i] = make_float4(h2, __expf(-sRv), __expf(-(sLv + attb)),
                                 __int_as_float(cl));
    }
}

// ---- kernel B: sparse aggregation + epilogue. One block per row i.
// 32 groups of 8 lanes; group gid handles neighbors n = gid, gid+32, ...
// (typical degree ~20 -> ONE round). Lane m owns dims [16m, 16m+16).
__global__ __launch_bounds__(256) void k_agg(
    const float* __restrict__ h, const float4* __restrict__ rowmeta,
    const int2* __restrict__ edge_g, float* __restrict__ out) {
    __shared__ __align__(16) float accS[32][132];
    __shared__ float sAs[32];
    __shared__ __align__(8) float accW[4][130];
    __shared__ float sAw[4];

    const int t = threadIdx.x, w = t >> 6, l = t & 63;
    const int gid = t >> 3, m = t & 7;
    const int i = blockIdx.x;

    const float4 rm = rowmeta[i];
    const int tot = __float_as_int(rm.w);
    const float h2_i = rm.x;
    const float EL_i = rm.z;
    const float B = 1.f - h2_i;
    const float cA = fmaxf(B, MINN);

    const float* hrow = h + (size_t)i * D + 16 * m;
    float4 hi0 = *(const float4*)(hrow);
    float4 hi1 = *(const float4*)(hrow + 4);
    float4 hi2 = *(const float4*)(hrow + 8);
    float4 hi3 = *(const float4*)(hrow + 12);

    float4 a0 = make_float4(0.f, 0.f, 0.f, 0.f);
    float4 a1 = make_float4(0.f, 0.f, 0.f, 0.f);
    float4 a2 = make_float4(0.f, 0.f, 0.f, 0.f);
    float4 a3 = make_float4(0.f, 0.f, 0.f, 0.f);
    float sAcc = 0.f;

    for (int n = gid; n < tot; n += 32) {
        int2 e = edge_g[i * CAP + n];
        const int j = e.x;
        const float aval = __int_as_float(e.y);
        const float* hj = h + (size_t)j * D + 16 * m;
        float4 hj0 = *(const float4*)(hj);
        float4 hj1 = *(const float4*)(hj + 4);
        float4 hj2 = *(const float4*)(hj + 8);
        float4 hj3 = *(const float4*)(hj + 12);
        float2 qj = *(const float2*)(&rowmeta[j]);  // (h2_j, e^-sR_j)

        float d = dot44(hi0, hj0) + dot44(hi1, hj1) + dot44(hi2, hj2) +
                  dot44(hi3, hj3);
        float dot = group8_sum(d);
        float h2_j = qj.x, ER_j = qj.y;
        float den = fmaxf(1.f - 2.f * dot + h2_i * h2_j, MINN);
        float p = __fdividef(-(1.f - 2.f * dot + h2_j), den);
        float qq = __fdividef(B, den);
        float n2 = p * p * h2_i + 2.f * p * qq * dot + qq * qq * h2_j;
        float nrm = fmaxf(sqrtf(fmaxf(n2, 0.f)), MINN);
        float coefc = cA * __fdividef(artanh_fast(nrm), nrm);
        float sig = __fdividef(1.f, 1.f + EL_i * ER_j);
        float wgt = aval * sig;
        sAcc += wgt * coefc * p;
        float wb = wgt * coefc * qq;
        a0.x += wb * hj0.x; a0.y += wb * hj0.y;
        a0.z += wb * hj0.z; a0.w += wb * hj0.w;
        a1.x += wb * hj1.x; a1.y += wb * hj1.y;
        a1.z += wb * hj1.z; a1.w += wb * hj1.w;
        a2.x += wb * hj2.x; a2.y += wb * hj2.y;
        a2.z += wb * hj2.z; a2.w += wb * hj2.w;
        a3.x += wb * hj3.x; a3.y += wb * hj3.y;
        a3.z += wb * hj3.z; a3.w += wb * hj3.w;
    }

    *(float4*)(&accS[gid][16 * m]) = a0;
    *(float4*)(&accS[gid][16 * m + 4]) = a1;
    *(float4*)(&accS[gid][16 * m + 8]) = a2;
    *(float4*)(&accS[gid][16 * m + 12]) = a3;
    if (m == 0) sAs[gid] = sAcc;
    __syncthreads();

    // ---- stage 1: wave w reduces its 8 groups; lane l owns dims (2l, 2l+1)
    {
        float b0 = 0.f, b1 = 0.f, psA = 0.f;
#pragma unroll
        for (int k = 0; k < 8; ++k) {
            const int g2 = (w << 3) + k;
            float2 v = *(const float2*)(&accS[g2][2 * l]);
            b0 += v.x;
            b1 += v.y;
            psA += sAs[g2];
        }
        *(float2*)(&accW[w][2 * l]) = make_float2(b0, b1);
        if (l == 0) sAw[w] = psA;
    }
    __syncthreads();

    if (w != 0) return;

    // ---- wave 0 epilogue: lane l owns dims (2l, 2l+1); ONE reduction total
    float2 v0 = *(const float2*)(&accW[0][2 * l]);
    float2 v1 = *(const float2*)(&accW[1][2 * l]);
    float2 v2 = *(const float2*)(&accW[2][2 * l]);
    float2 v3 = *(const float2*)(&accW[3][2 * l]);
    float b0 = v0.x + v1.x + v2.x + v3.x;
    float b1 = v0.y + v1.y + v2.y + v3.y;
    float sA = sAw[0] + sAw[1] + sAw[2] + sAw[3];

    float2 hi = *(const float2*)(h + (size_t)i * D + 2 * l);
    float u0 = sA * hi.x + b0, u1 = sA * hi.y + b1;

    float u2 = u0 * u0 + u1 * u1;
    float hiu = hi.x * u0 + hi.y * u1;
    wave_sum2(u2, hiu);
    float un = fmaxf(sqrtf(u2), MINN);
    float lam = 2.f / cA;
    float th = tanh_pos(0.5f * lam * un);
    float r = th / un;
    float s0 = r * u0, s1 = r * u1;
    float y2 = th * th;
    float xy = r * hiu;
    float den2 = fmaxf(1.f + 2.f * xy + h2_i * y2, MINN);
    float c1 = (1.f + 2.f * xy + y2) / den2;
    float c2 = (1.f - h2_i) / den2;
    float hp0 = c1 * hi.x + c2 * s0;
    float hp1 = c1 * hi.y + c2 * s1;
    // |hp|^2 analytically: <hi,s> = xy, |s|^2 = y2 — no reduction needed
    float hn2 = c1 * c1 * h2_i + 2.f * c1 * c2 * xy + c2 * c2 * y2;
    float hn = fmaxf(sqrtf(hn2), MINN);
    float scl = (hn > MAXNORM) ? (MAXNORM / hn) : 1.f;
    hp0 *= scl;
    hp1 *= scl;
    float n3 = fminf(fmaxf(hn, MINN), MAXNORM);
    float tn3 = tanh_pos(n3);
    float fac = __fdividef(tn3, n3);
    float o0 = fac * hp0, o1 = fac * hp1;
    if (tn3 > MAXNORM) {
        float ss = MAXNORM / tn3;
        o0 *= ss;
        o1 *= ss;
    }
    *(float2*)(out + (size_t)i * D + 2 * l) = make_float2(o0, o1);
}

extern "C" void kernel_launch(void* const* d_in, const int* in_sizes, int n_in,
                              void* d_out, int out_size, void* d_ws, size_t ws_size,
                              hipStream_t stream) {
    const float* x = (const float*)d_in[0];
    const float* adj = (const float*)d_in[1];
    const float* Wm = (const float*)d_in[2];
    const float* bias = (const float*)d_in[3];
    const float* attw = (const float*)d_in[4];
    const float* attb = (const float*)d_in[5];
    float* out = (float*)d_out;

    float* ws = (float*)d_ws;
    float* h = ws;                                   // N*D floats
    float4* rowmeta = (float4*)(h + (size_t)N * D);  // N float4
    int2* edge_g = (int2*)(rowmeta + N);             // N*CAP int2 (j, aval)

    hipLaunchKernelGGL(k_rows, dim3(N / 2), dim3(256), 0, stream, x, Wm, bias,
                       attw, attb, adj, h, rowmeta, edge_g);
    hipLaunchKernelGGL(k_agg, dim3(N), dim3(256), 0, stream, h, rowmeta,
                       edge_g, out);
}

// Round 15
// 16.547 us; speedup vs baseline: 1.0866x; 1.0866x over previous
//
#include <hip/hip_runtime.h>
#include <math.h>

#define N 1024
#define D 128
#define CAP 96
#define MAXNORM 0.996f
#define MINN 1e-15f

__device__ __forceinline__ float wave_sum(float v) {
#pragma unroll
    for (int o = 32; o > 0; o >>= 1) v += __shfl_xor(v, o, 64);
    return v;
}

__device__ __forceinline__ void wave_sum2(float& a, float& b) {
#pragma unroll
    for (int o = 32; o > 0; o >>= 1) {
        a += __shfl_xor(a, o, 64);
        b += __shfl_xor(b, o, 64);
    }
}

__device__ __forceinline__ void wave_sum3(float& a, float& b, float& c) {
#pragma unroll
    for (int o = 32; o > 0; o >>= 1) {
        a += __shfl_xor(a, o, 64);
        b += __shfl_xor(b, o, 64);
        c += __shfl_xor(c, o, 64);
    }
}

__device__ __forceinline__ float group16_sum(float v) {
#pragma unroll
    for (int o = 8; o > 0; o >>= 1) v += __shfl_xor(v, o, 64);
    return v;
}

__device__ __forceinline__ float group8_sum(float v) {
#pragma unroll
    for (int o = 4; o > 0; o >>= 1) v += __shfl_xor(v, o, 64);
    return v;
}

__device__ __forceinline__ float artanh_fast(float x) {
    x = fminf(fmaxf(x, -1.0f + 1e-7f), 1.0f - 1e-7f);
    return 0.5f * __logf(__fdividef(1.0f + x, 1.0f - x));
}

// tanh for x >= 0 via one v_exp: (1 - e^-2x) / (1 + e^-2x)
__device__ __forceinline__ float tanh_pos(float x) {
    float t = __expf(-2.f * x);
    return __fdividef(1.f - t, 1.f + t);
}

// ---- kernel A: one block (4 waves) per row i.
// h row, rowmeta = (h2, e^-sR, e^-(sL+attb), cnt), adj-row CSR edges.
__global__ __launch_bounds__(256) void k_rows(
    const float* __restrict__ x, const float* __restrict__ Wm,
    const float* __restrict__ bias, const float* __restrict__ attw,
    const float* __restrict__ attb_p, const float* __restrict__ adj,
    float* __restrict__ h, float4* __restrict__ rowmeta,
    int2* __restrict__ edge_g) {
    __shared__ float smv[D];
    __shared__ int wcnt[4];
    const int t = threadIdx.x, w = t >> 6, l = t & 63;
    const int g = l >> 4, m = l & 15;
    const int i = blockIdx.x;
    const unsigned long long lt_mask = (1ull << l) - 1ull;

    // issue adj-row segment load early (hides HBM latency under the matvec)
    float4 av = *(const float4*)(adj + (size_t)i * N + (w << 8) + 4 * l);

    // x-row chunks (reused across all 8 matvec passes)
    float4 xa = *(const float4*)(x + (size_t)i * D + 4 * m);
    float4 xb = *(const float4*)(x + (size_t)i * D + 64 + 4 * m);

    float xn2 = group16_sum(xa.x * xa.x + xa.y * xa.y + xa.z * xa.z +
                            xa.w * xa.w + xb.x * xb.x + xb.y * xb.y +
                            xb.z * xb.z + xb.w * xb.w);

    // matvec: wave w covers outputs [32w,32w+32); group g does output 32w+4p+g
#pragma unroll
    for (int p = 0; p < 8; ++p) {
        const int o = (w << 5) + (p << 2) + g;
        float4 wa = *(const float4*)(Wm + (size_t)o * D + 4 * m);
        float4 wb = *(const float4*)(Wm + (size_t)o * D + 64 + 4 * m);
        float s = xa.x * wa.x + xa.y * wa.y + xa.z * wa.z + xa.w * wa.w +
                  xb.x * wb.x + xb.y * wb.y + xb.z * wb.z + xb.w * wb.w;
        s = group16_sum(s);
        if (m == 0) smv[o] = s;
    }

    // ballot compaction bookkeeping
    float ae[4] = {av.x, av.y, av.z, av.w};
    unsigned long long msk[4];
    int cnt = 0;
#pragma unroll
    for (int e = 0; e < 4; ++e) {
        msk[e] = __ballot(ae[e] != 0.0f);
        cnt += __popcll(msk[e]);
    }
    if (l == 0) wcnt[w] = cnt;
    __syncthreads();  // [A] publishes smv and wcnt

    int base = 0;
#pragma unroll
    for (int ww = 0; ww < 4; ++ww)
        if (ww < w) base += wcnt[ww];
    const int tot = wcnt[0] + wcnt[1] + wcnt[2] + wcnt[3];
    {
        int off = base;
#pragma unroll
        for (int e = 0; e < 4; ++e) {
            if (ae[e] != 0.0f) {
                int pos = off + __popcll(msk[e] & lt_mask);
                if (pos < CAP)
                    edge_g[i * CAP + pos] =
                        make_int2((w << 8) + 4 * l + e, __float_as_int(ae[e]));
            }
            off += __popcll(msk[e]);
        }
    }

    if (w != 0) return;

    // ---- wave 0: TWO serial reduction stages total.
    const float attb = attb_p[0];
    float2 bv = *(const float2*)(bias + 2 * l);
    float2 mv = *(const float2*)(&smv[2 * l]);

    // stage 1: (|mv|^2, |bias|^2, <mv,bias>) batched
    float mxn2 = mv.x * mv.x + mv.y * mv.y;
    float bn2 = bv.x * bv.x + bv.y * bv.y;
    float mvb = mv.x * bv.x + mv.y * bv.y;
    wave_sum3(mxn2, bn2, mvb);

    // bias chain (all scalar): hbv = hbs * bv
    float bn = fmaxf(sqrtf(bn2), MINN);
    float tb = tanh_pos(bn);
    float bsc = tb / bn;
    float clampB = (tb > MAXNORM) ? (MAXNORM / tb) : 1.f;
    float hbs = bsc * clampB;
    float vn = fminf(tb, MAXNORM);
    float y2 = vn * vn;

    // mobius_matvec norm chain (scalar): r = rs * mv
    float mxn = fmaxf(sqrtf(mxn2), MINN);
    float xn = fmaxf(sqrtf(xn2), MINN);
    float rn = tanh_pos(mxn / xn * artanh_fast(xn));  // = |mobius_matvec| >= 0
    float rsc = rn / mxn;
    float sr = (rn > MAXNORM) ? (MAXNORM / rn) : 1.f;
    float rs = rsc * sr;
    float rn_c = rn * sr;
    float x2 = rn_c * rn_c;

    // mobius_add(r, hbv): <r,hbv> = rs*hbs*<mv,bv> (scalar — no reduction)
    float xy = rs * hbs * mvb;
    float den = fmaxf(1.f + 2.f * xy + x2 * y2, MINN);
    float ca = (1.f + 2.f * xy + y2) / den;
    float cb = (1.f - x2) / den;
    float hp0 = ca * rs * mv.x + cb * hbs * bv.x;
    float hp1 = ca * rs * mv.y + cb * hbs * bv.y;

    // stage 2: (|hp|^2, hp.wl, hp.wr) batched on UNSCALED hp (proj is linear)
    float t0 = hp0 * hp0 + hp1 * hp1;
    float t1 = hp0 * attw[2 * l] + hp1 * attw[2 * l + 1];
    float t2 = hp0 * attw[D + 2 * l] + hp1 * attw[D + 2 * l + 1];
    wave_sum3(t0, t1, t2);

    float hn = fmaxf(sqrtf(t0), MINN);
    float sh = (hn > MAXNORM) ? (MAXNORM / hn) : 1.f;
    hp0 *= sh; hp1 *= sh;
    float h2 = t0 * sh * sh;
    float hnn = fmaxf(sqrtf(h2), MINN);
    float fac = artanh_fast(hnn) / hnn;
    float sLv = fac * (t1 * sh);
    float sRv = fac * (t2 * sh);

    *(float2*)(h + (size_t)i * D + 2 * l) = make_float2(hp0, hp1);
    if (l == 0) {
        int cl = (tot < CAP) ? tot : CAP;
        rowmeta[i] = make_float4(h2, __expf(-sRv), __expf(-(sLv + attb)),
                                 __int_as_float(cl));
    }
}

// ---- kernel B: sparse aggregation + epilogue. One block per row i.
// 32 groups of 8 lanes; group gid handles neighbors n = gid, gid+32, ...
// (typical degree ~20 -> ONE round). Lane m owns dims [16m, 16m+16).
__global__ __launch_bounds__(256) void k_agg(
    const float* __restrict__ h, const float4* __restrict__ rowmeta,
    const int2* __restrict__ edge_g, float* __restrict__ out) {
    __shared__ __align__(16) float accS[32][132];
    __shared__ float sAs[32];
    __shared__ __align__(8) float accW[4][130];
    __shared__ float sAw[4];

    const int t = threadIdx.x, w = t >> 6, l = t & 63;
    const int gid = t >> 3, m = t & 7;
    const int i = blockIdx.x;

    const float4 rm = rowmeta[i];
    const int tot = __float_as_int(rm.w);
    const float h2_i = rm.x;
    const float EL_i = rm.z;
    const float B = 1.f - h2_i;
    const float cA = fmaxf(B, MINN);

    const float* hrow = h + (size_t)i * D + 16 * m;
    float4 hi0 = *(const float4*)(hrow);
    float4 hi1 = *(const float4*)(hrow + 4);
    float4 hi2 = *(const float4*)(hrow + 8);
    float4 hi3 = *(const float4*)(hrow + 12);

    float4 a0 = make_float4(0.f, 0.f, 0.f, 0.f);
    float4 a1 = make_float4(0.f, 0.f, 0.f, 0.f);
    float4 a2 = make_float4(0.f, 0.f, 0.f, 0.f);
    float4 a3 = make_float4(0.f, 0.f, 0.f, 0.f);
    float sAcc = 0.f;

    for (int n = gid; n < tot; n += 32) {
        int2 e = edge_g[i * CAP + n];
        const int j = e.x;
        const float aval = __int_as_float(e.y);
        const float* hj = h + (size_t)j * D + 16 * m;
        float4 hj0 = *(const float4*)(hj);
        float4 hj1 = *(const float4*)(hj + 4);
        float4 hj2 = *(const float4*)(hj + 8);
        float4 hj3 = *(const float4*)(hj + 12);
        float2 qj = *(const float2*)(&rowmeta[j]);  // (h2_j, e^-sR_j)

        float d = hi0.x * hj0.x + hi0.y * hj0.y + hi0.z * hj0.z +
                  hi0.w * hj0.w + hi1.x * hj1.x + hi1.y * hj1.y +
                  hi1.z * hj1.z + hi1.w * hj1.w + hi2.x * hj2.x +
                  hi2.y * hj2.y + hi2.z * hj2.z + hi2.w * hj2.w +
                  hi3.x * hj3.x + hi3.y * hj3.y + hi3.z * hj3.z +
                  hi3.w * hj3.w;
        float dot = group8_sum(d);
        float h2_j = qj.x, ER_j = qj.y;
        float den = fmaxf(1.f - 2.f * dot + h2_i * h2_j, MINN);
        float p = __fdividef(-(1.f - 2.f * dot + h2_j), den);
        float qq = __fdividef(B, den);
        float n2 = p * p * h2_i + 2.f * p * qq * dot + qq * qq * h2_j;
        float nrm = fmaxf(sqrtf(fmaxf(n2, 0.f)), MINN);
        float coefc = cA * __fdividef(artanh_fast(nrm), nrm);
        float sig = __fdividef(1.f, 1.f + EL_i * ER_j);
        float wgt = aval * sig;
        sAcc += wgt * coefc * p;
        float wb = wgt * coefc * qq;
        a0.x += wb * hj0.x; a0.y += wb * hj0.y;
        a0.z += wb * hj0.z; a0.w += wb * hj0.w;
        a1.x += wb * hj1.x; a1.y += wb * hj1.y;
        a1.z += wb * hj1.z; a1.w += wb * hj1.w;
        a2.x += wb * hj2.x; a2.y += wb * hj2.y;
        a2.z += wb * hj2.z; a2.w += wb * hj2.w;
        a3.x += wb * hj3.x; a3.y += wb * hj3.y;
        a3.z += wb * hj3.z; a3.w += wb * hj3.w;
    }

    *(float4*)(&accS[gid][16 * m]) = a0;
    *(float4*)(&accS[gid][16 * m + 4]) = a1;
    *(float4*)(&accS[gid][16 * m + 8]) = a2;
    *(float4*)(&accS[gid][16 * m + 12]) = a3;
    if (m == 0) sAs[gid] = sAcc;
    __syncthreads();

    // ---- stage 1: wave w reduces its 8 groups; lane l owns dims (2l, 2l+1)
    {
        float b0 = 0.f, b1 = 0.f, psA = 0.f;
#pragma unroll
        for (int k = 0; k < 8; ++k) {
            const int g2 = (w << 3) + k;
            float2 v = *(const float2*)(&accS[g2][2 * l]);
            b0 += v.x;
            b1 += v.y;
            psA += sAs[g2];
        }
        *(float2*)(&accW[w][2 * l]) = make_float2(b0, b1);
        if (l == 0) sAw[w] = psA;
    }
    __syncthreads();

    if (w != 0) return;

    // ---- wave 0 epilogue: lane l owns dims (2l, 2l+1); ONE reduction total
    float2 v0 = *(const float2*)(&accW[0][2 * l]);
    float2 v1 = *(const float2*)(&accW[1][2 * l]);
    float2 v2 = *(const float2*)(&accW[2][2 * l]);
    float2 v3 = *(const float2*)(&accW[3][2 * l]);
    float b0 = v0.x + v1.x + v2.x + v3.x;
    float b1 = v0.y + v1.y + v2.y + v3.y;
    float sA = sAw[0] + sAw[1] + sAw[2] + sAw[3];

    float2 hi = *(const float2*)(h + (size_t)i * D + 2 * l);
    float u0 = sA * hi.x + b0, u1 = sA * hi.y + b1;

    float u2 = u0 * u0 + u1 * u1;
    float hiu = hi.x * u0 + hi.y * u1;
    wave_sum2(u2, hiu);
    float un = fmaxf(sqrtf(u2), MINN);
    float lam = 2.f / cA;
    float th = tanh_pos(0.5f * lam * un);
    float r = th / un;
    float s0 = r * u0, s1 = r * u1;
    float y2 = th * th;
    float xy = r * hiu;
    float den2 = fmaxf(1.f + 2.f * xy + h2_i * y2, MINN);
    float c1 = (1.f + 2.f * xy + y2) / den2;
    float c2 = (1.f - h2_i) / den2;
    float hp0 = c1 * hi.x + c2 * s0;
    float hp1 = c1 * hi.y + c2 * s1;
    // |hp|^2 analytically: <hi,s> = xy, |s|^2 = y2 — no reduction needed
    float hn2 = c1 * c1 * h2_i + 2.f * c1 * c2 * xy + c2 * c2 * y2;
    float hn = fmaxf(sqrtf(hn2), MINN);
    float scl = (hn > MAXNORM) ? (MAXNORM / hn) : 1.f;
    hp0 *= scl; hp1 *= scl;
    float n3 = fminf(fmaxf(hn, MINN), MAXNORM);
    float tn3 = tanh_pos(n3);
    float fac = __fdividef(tn3, n3);
    float o0 = fac * hp0, o1 = fac * hp1;
    if (tn3 > MAXNORM) {
        float ss = MAXNORM / tn3;
        o0 *= ss; o1 *= ss;
    }
    *(float2*)(out + (size_t)i * D + 2 * l) = make_float2(o0, o1);
}

extern "C" void kernel_launch(void* const* d_in, const int* in_sizes, int n_in,
                              void* d_out, int out_size, void* d_ws, size_t ws_size,
                              hipStream_t stream) {
    const float* x = (const float*)d_in[0];
    const float* adj = (const float*)d_in[1];
    const float* Wm = (const float*)d_in[2];
    const float* bias = (const float*)d_in[3];
    const float* attw = (const float*)d_in[4];
    const float* attb = (const float*)d_in[5];
    float* out = (float*)d_out;

    float* ws = (float*)d_ws;
    float* h = ws;                                   // N*D floats
    float4* rowmeta = (float4*)(h + (size_t)N * D);  // N float4
    int2* edge_g = (int2*)(rowmeta + N);             // N*CAP int2 (j, aval)

    hipLaunchKernelGGL(k_rows, dim3(N), dim3(256), 0, stream, x, Wm, bias,
                       attw, attb, adj, h, rowmeta, edge_g);
    hipLaunchKernelGGL(k_agg, dim3(N), dim3(256), 0, stream, h, rowmeta,
                       edge_g, out);
}